// Round 1
// baseline (1309.756 us; speedup 1.0000x reference)
//
#include <hip/hip_runtime.h>
#include <hip/hip_bf16.h>

#define DIM 384
#define HEADS 8
#define CP 48
#define NB 4
#define HIMG 128
#define WIMG 128
#define HW 16384

using bf16 = __hip_bfloat16;

__device__ __forceinline__ float lo_bf(unsigned u){ union{unsigned i; float f;} c; c.i = u<<16; return c.f; }
__device__ __forceinline__ float hi_bf(unsigned u){ union{unsigned i; float f;} c; c.i = u & 0xffff0000u; return c.f; }
__device__ __forceinline__ bf16 f2bf(float v){ return __float2bfloat16(v); }

__device__ __forceinline__ float4 load4f(const float* p){ return *(const float4*)p; }
__device__ __forceinline__ float4 load4f(const bf16* p){
  uint2 u = *(const uint2*)p;
  float4 r; r.x = lo_bf(u.x); r.y = hi_bf(u.x); r.z = lo_bf(u.y); r.w = hi_bf(u.y); return r;
}
__device__ __forceinline__ void store4f(float* p, float4 v){ *(float4*)p = v; }
__device__ __forceinline__ void store4f(bf16* p, float4 v){
  union { bf16 h[4]; uint2 u; } pk;
  pk.h[0]=f2bf(v.x); pk.h[1]=f2bf(v.y); pk.h[2]=f2bf(v.z); pk.h[3]=f2bf(v.w);
  *(uint2*)p = pk.u;
}

// C[b][m][n] = sum_k A[b][m][k] * B[b][k][n];  N per batch = HW (16384)
// A fp32 (aStride==0 -> shared across batch), B/C templated.
template<typename TB, typename TOut>
__global__ __launch_bounds__(256) void gemm1x1(
    const float* __restrict__ A, long aStride,
    const TB* __restrict__ Bm, TOut* __restrict__ Cm,
    int M, int K)
{
  const int b  = blockIdx.z;
  const int m0 = blockIdx.y * 64;
  const int n0 = blockIdx.x * 64;
  const float* Ab = A + (long)b * aStride;
  const TB*    Bb = Bm + (long)b * K * HW;
  TOut*        Cb = Cm + (long)b * M * HW;

  __shared__ float As[16][68]; // As[k][m], padded
  __shared__ float Bs[16][64]; // Bs[k][n]

  const int t  = threadIdx.x;
  const int ty = t >> 4, tx = t & 15;
  const int am = t >> 2;
  const int ak = (t & 3) * 4;
  const int bk = t >> 4;
  const int bn = (t & 15) * 4;

  float acc[4][4] = {};

  for (int k0 = 0; k0 < K; k0 += 16) {
    float4 av = *(const float4*)(Ab + (long)(m0 + am) * K + (k0 + ak));
    As[ak+0][am] = av.x; As[ak+1][am] = av.y; As[ak+2][am] = av.z; As[ak+3][am] = av.w;
    float4 bv = load4f(Bb + (long)(k0 + bk) * HW + (n0 + bn));
    *(float4*)&Bs[bk][bn] = bv;
    __syncthreads();
#pragma unroll
    for (int k = 0; k < 16; ++k) {
      float4 a  = *(const float4*)&As[k][ty*4];
      float4 bb = *(const float4*)&Bs[k][tx*4];
      float ar[4] = {a.x, a.y, a.z, a.w};
      float br[4] = {bb.x, bb.y, bb.z, bb.w};
#pragma unroll
      for (int i = 0; i < 4; ++i)
#pragma unroll
        for (int j = 0; j < 4; ++j) acc[i][j] += ar[i] * br[j];
    }
    __syncthreads();
  }
#pragma unroll
  for (int i = 0; i < 4; ++i) {
    float4 v = make_float4(acc[i][0], acc[i][1], acc[i][2], acc[i][3]);
    store4f(&Cb[(long)(m0 + ty*4 + i) * HW + n0 + tx*4], v);
  }
}

// depthwise 3x3 SAME on 1152 logical channels (q:0..383 from qb, k/v from kvb),
// also accumulates sum-of-squares per (b, channel) for q & k channels.
__global__ __launch_bounds__(256) void dwconv(
    const bf16* __restrict__ qb, const bf16* __restrict__ kvb,
    const float* __restrict__ Wdw,
    bf16* __restrict__ qd, bf16* __restrict__ kd, bf16* __restrict__ vd,
    float* __restrict__ ssq)
{
  const int rblk = blockIdx.x;   // 0..7 (16 rows each)
  const int ch   = blockIdx.y;   // 0..1151
  const int b    = blockIdx.z;
  const int r0   = rblk * 16;
  const bf16* src = (ch < DIM) ? qb  + ((long)b*DIM  + ch)*HW
                               : kvb + ((long)b*2*DIM + (ch - DIM))*HW;
  float w[9];
#pragma unroll
  for (int i = 0; i < 9; ++i) w[i] = Wdw[ch*9 + i];

  __shared__ float tile[18][130];
  const int t = threadIdx.x;
  if (t < 36) tile[t>>1][(t&1)*129] = 0.f;
#pragma unroll
  for (int i = 0; i < 5; ++i) {
    int idx = t + 256*i;
    if (idx < 1152) {
      int row = idx >> 6;       // 0..17
      int cp2 = idx & 63;       // uint pair within row
      int gr  = r0 - 1 + row;
      float v0 = 0.f, v1 = 0.f;
      if (gr >= 0 && gr < HIMG) {
        unsigned u = *(const unsigned*)(src + (long)gr*WIMG + cp2*2);
        v0 = lo_bf(u); v1 = hi_bf(u);
      }
      tile[row][1 + cp2*2] = v0;
      tile[row][2 + cp2*2] = v1;
    }
  }
  __syncthreads();

  bf16* dst;
  if (ch < DIM)        dst = qd + ((long)b*DIM + ch)*HW;
  else if (ch < 2*DIM) dst = kd + ((long)b*DIM + (ch - DIM))*HW;
  else                 dst = vd + ((long)b*DIM + (ch - 2*DIM))*HW;

  float ss = 0.f;
#pragma unroll
  for (int i = 0; i < 8; ++i) {
    int idx = t + 256*i;
    int rr = idx >> 7;          // 0..15
    int cc = idx & 127;
    float acc = 0.f;
#pragma unroll
    for (int ky = 0; ky < 3; ++ky)
#pragma unroll
      for (int kx = 0; kx < 3; ++kx)
        acc += w[ky*3 + kx] * tile[rr + ky][cc + kx];
    dst[(long)(r0 + rr)*WIMG + cc] = f2bf(acc);
    ss += acc * acc;
  }

  if (ch < 2*DIM) {
#pragma unroll
    for (int off = 32; off; off >>= 1) ss += __shfl_down(ss, off);
    __shared__ float wsum[4];
    if ((t & 63) == 0) wsum[t >> 6] = ss;
    __syncthreads();
    if (t == 0) atomicAdd(&ssq[b*2*DIM + ch], wsum[0]+wsum[1]+wsum[2]+wsum[3]);
  }
}

// partial S[b,h,c,d] += sum over n-chunk of qd[c,n]*kd[d,n]
__global__ __launch_bounds__(256) void s_partial(
    const bf16* __restrict__ qd, const bf16* __restrict__ kd,
    float* __restrict__ S)
{
  const int chunk = blockIdx.x;  // 0..7, 2048 n each
  const int h = blockIdx.y;
  const int b = blockIdx.z;
  const int n_base = chunk * 2048;
  const bf16* qp = qd + ((long)b*DIM + h*CP)*HW;
  const bf16* kp = kd + ((long)b*DIM + h*CP)*HW;

  __shared__ float qs[48][130];
  __shared__ float ks[48][130];
  const int t  = threadIdx.x;
  const int ty = t >> 4, tx = t & 15;
  float acc[3][3] = {};

  for (int tile0 = 0; tile0 < 2048; tile0 += 128) {
    const int n0 = n_base + tile0;
#pragma unroll
    for (int i = 0; i < 12; ++i) {
      int idx = t + 256*i;       // 0..3071
      int row = idx >> 6;        // 0..47
      int cp2 = idx & 63;
      unsigned uq = *(const unsigned*)(qp + (long)row*HW + n0 + cp2*2);
      unsigned uk = *(const unsigned*)(kp + (long)row*HW + n0 + cp2*2);
      qs[row][cp2*2] = lo_bf(uq); qs[row][cp2*2+1] = hi_bf(uq);
      ks[row][cp2*2] = lo_bf(uk); ks[row][cp2*2+1] = hi_bf(uk);
    }
    __syncthreads();
    for (int n = 0; n < 128; ++n) {
      float qv[3], kv[3];
#pragma unroll
      for (int i = 0; i < 3; ++i) qv[i] = qs[ty*3+i][n];
#pragma unroll
      for (int j = 0; j < 3; ++j) kv[j] = ks[tx*3+j][n];
#pragma unroll
      for (int i = 0; i < 3; ++i)
#pragma unroll
        for (int j = 0; j < 3; ++j) acc[i][j] += qv[i]*kv[j];
    }
    __syncthreads();
  }
  float* Sp = S + ((long)(b*HEADS + h))*CP*CP;
#pragma unroll
  for (int i = 0; i < 3; ++i)
#pragma unroll
    for (int j = 0; j < 3; ++j)
      atomicAdd(&Sp[(ty*3+i)*CP + tx*3+j], acc[i][j]);
}

// logit = S * rsqrt(ssq_q[c]) * rsqrt(ssq_k[d]) * temp[h]; softmax over d (in place)
__global__ __launch_bounds__(64) void softmax_attn(
    float* __restrict__ S, const float* __restrict__ ssq,
    const float* __restrict__ temp)
{
  const int bhc = blockIdx.x;
  const int c = bhc % CP;
  const int h = (bhc / CP) % HEADS;
  const int b = bhc / (CP * HEADS);
  const int lane = threadIdx.x;
  float* row = S + (((long)(b*HEADS + h))*CP + c)*CP;
  const float rq = rsqrtf(ssq[b*2*DIM + h*CP + c]);
  const float tmp = temp[h];
  float logit = -1e30f;
  if (lane < CP) {
    float rk = rsqrtf(ssq[b*2*DIM + DIM + h*CP + lane]);
    logit = row[lane] * rq * rk * tmp;
  }
  float m = logit;
#pragma unroll
  for (int off = 32; off; off >>= 1) m = fmaxf(m, __shfl_down(m, off));
  m = __shfl(m, 0);
  float e = (lane < CP) ? __expf(logit - m) : 0.f;
  float s = e;
#pragma unroll
  for (int off = 32; off; off >>= 1) s += __shfl_down(s, off);
  s = __shfl(s, 0);
  if (lane < CP) row[lane] = e / s;
}

// W2[b, o, h*48+d] = sum_c Wproj[o, h*48+c] * attn[b,h,c,d]
__global__ __launch_bounds__(256) void w2fold(
    const float* __restrict__ attn, const float* __restrict__ Wproj,
    float* __restrict__ W2)
{
  const int ot = blockIdx.x;  // o-tile of 128 (3 tiles)
  const int h  = blockIdx.y;
  const int b  = blockIdx.z;
  __shared__ float at[48][48];
  __shared__ float wp[128][48];
  const int t = threadIdx.x;
  const float* Ap = attn + ((long)(b*HEADS + h))*CP*CP;
#pragma unroll
  for (int i = 0; i < 9; ++i) {
    int idx = t + 256*i;  // 0..2303
    at[idx / 48][idx % 48] = Ap[idx];
  }
#pragma unroll
  for (int i = 0; i < 24; ++i) {
    int idx = t + 256*i;  // 0..6143
    int o = idx / 48, c = idx % 48;
    wp[o][c] = Wproj[(long)(ot*128 + o)*DIM + h*CP + c];
  }
  __syncthreads();
#pragma unroll
  for (int i = 0; i < 24; ++i) {
    int idx = t + 256*i;
    int o = idx / 48, d = idx % 48;
    float a = 0.f;
#pragma unroll
    for (int c = 0; c < 48; ++c) a += wp[o][c] * at[c][d];
    W2[((long)b*DIM + ot*128 + o)*DIM + h*CP + d] = a;
  }
}

extern "C" void kernel_launch(void* const* d_in, const int* in_sizes, int n_in,
                              void* d_out, int out_size, void* d_ws, size_t ws_size,
                              hipStream_t stream) {
  const float* x     = (const float*)d_in[0];
  const float* y     = (const float*)d_in[1];
  const float* Wq    = (const float*)d_in[2];
  const float* Wkv   = (const float*)d_in[3];
  const float* Wdw   = (const float*)d_in[4];
  const float* Wproj = (const float*)d_in[5];
  const float* temp  = (const float*)d_in[6];
  float* out = (float*)d_out;

  char* ws = (char*)d_ws;
  bf16*  q_bf  = (bf16*)(ws + 0L);           // 4*384*16384*2  = 50331648
  bf16*  kv_bf = (bf16*)(ws + 50331648L);    // 4*768*16384*2  = 100663296
  bf16*  qd    = (bf16*)(ws + 150994944L);   // 50331648
  bf16*  kd    = (bf16*)(ws + 201326592L);   // 50331648
  bf16*  vd    = (bf16*)(ws + 251658240L);   // 50331648
  float* ssq   = (float*)(ws + 301989888L);  // 4*768*4 = 12288
  float* S     = (float*)(ws + 302002176L);  // 4*8*48*48*4 = 294912
  float* W2    = (float*)(ws + 302297088L);  // 4*384*384*4 = 2359296
  // total: 304656384 bytes

  hipMemsetAsync(ssq, 0, 4*2*DIM*sizeof(float), stream);
  hipMemsetAsync(S, 0, (long)NB*HEADS*CP*CP*sizeof(float), stream);

  // q = Wq @ x ; kv = Wkv @ y   (per batch, N=HW)
  gemm1x1<float, bf16><<<dim3(HW/64, DIM/64, NB), 256, 0, stream>>>(Wq, 0, x, q_bf, DIM, DIM);
  gemm1x1<float, bf16><<<dim3(HW/64, 2*DIM/64, NB), 256, 0, stream>>>(Wkv, 0, y, kv_bf, 2*DIM, DIM);
  // depthwise 3x3 + per-channel sumsq for q,k
  dwconv<<<dim3(HIMG/16, 3*DIM, NB), 256, 0, stream>>>(q_bf, kv_bf, Wdw, qd, kd, vd, ssq);
  // raw scores
  s_partial<<<dim3(8, HEADS, NB), 256, 0, stream>>>(qd, kd, S);
  // softmax with folded l2norm + temperature
  softmax_attn<<<dim3(NB*HEADS*CP), 64, 0, stream>>>(S, ssq, temp);
  // fold Wproj through attn
  w2fold<<<dim3(3, HEADS, NB), 256, 0, stream>>>(S, Wproj, W2);
  // Out = W2 @ vd  (per batch)
  gemm1x1<bf16, float><<<dim3(HW/64, DIM/64, NB), 256, 0, stream>>>(W2, (long)DIM*DIM, vd, out, DIM, DIM);
}

// Round 2
// 560.746 us; speedup vs baseline: 2.3357x; 2.3357x over previous
//
#include <hip/hip_runtime.h>
#include <hip/hip_bf16.h>

#define DIM 384
#define HEADS 8
#define CP 48
#define NB 4
#define HIMG 128
#define WIMG 128
#define HW 16384

using bf16 = __hip_bfloat16;

typedef __attribute__((ext_vector_type(8))) short bf16x8;
typedef __attribute__((ext_vector_type(4))) float f32x4;

__device__ __forceinline__ float lo_bf(unsigned u){ union{unsigned i; float f;} c; c.i = u<<16; return c.f; }
__device__ __forceinline__ float hi_bf(unsigned u){ union{unsigned i; float f;} c; c.i = u & 0xffff0000u; return c.f; }
__device__ __forceinline__ bf16 f2bf(float v){ return __float2bfloat16(v); }
__device__ __forceinline__ unsigned short bfbits(float v){ union{ bf16 h; unsigned short u; } c; c.h = f2bf(v); return c.u; }

__device__ __forceinline__ float4 load4f(const float* p){ return *(const float4*)p; }
__device__ __forceinline__ float4 load4f(const bf16* p){
  uint2 u = *(const uint2*)p;
  float4 r; r.x = lo_bf(u.x); r.y = hi_bf(u.x); r.z = lo_bf(u.y); r.w = hi_bf(u.y); return r;
}

__device__ __forceinline__ void st(float* p, float v){ *p = v; }
__device__ __forceinline__ void st(bf16* p, float v){ *p = f2bf(v); }

#define GLD_LDS16(g, l) __builtin_amdgcn_global_load_lds( \
    (const __attribute__((address_space(1))) void*)(g), \
    (__attribute__((address_space(3))) void*)(l), 16, 0, 0)

// ---------------------------------------------------------------------------
// Weight fp32 -> bf16 (Wq 384x384, Wkv 768x384), one launch.
__global__ __launch_bounds__(256) void convert_w(
    const float* __restrict__ Wq, const float* __restrict__ Wkv,
    bf16* __restrict__ Wq_bf, bf16* __restrict__ Wkv_bf)
{
  int idx = (blockIdx.x*256 + threadIdx.x) * 2;
  const int NQ = DIM*DIM;           // 147456
  const int NKV = 2*DIM*DIM;        // 294912
  if (idx < NQ) {
    unsigned u = (unsigned)bfbits(Wq[idx]) | ((unsigned)bfbits(Wq[idx+1]) << 16);
    *(unsigned*)(Wq_bf + idx) = u;
  } else {
    int j = idx - NQ;
    if (j < NKV) {
      unsigned u = (unsigned)bfbits(Wkv[j]) | ((unsigned)bfbits(Wkv[j+1]) << 16);
      *(unsigned*)(Wkv_bf + j) = u;
    }
  }
}

// ---------------------------------------------------------------------------
// Transpose + cast: in [C][HW] (TIn) -> out [HW][C] (bf16). 64x64 tiles.
// For TIn=float: gridDim.z = 8 (z<4 -> tensor0, else tensor1).
template<typename TIn>
__global__ __launch_bounds__(256) void transpose_cast(
    const TIn* __restrict__ in0, const TIn* __restrict__ in1,
    bf16* __restrict__ out0, bf16* __restrict__ out1,
    long inBatchStride, long outBatchStride)
{
  const int zb = blockIdx.z;
  const TIn* in = (zb < NB) ? in0 : in1;
  bf16* outp = (zb < NB) ? out0 : out1;
  const int b = zb & 3;
  const int n0 = blockIdx.x * 64;
  const int c0 = blockIdx.y * 64;
  const TIn* inb = in + (long)b * inBatchStride;
  bf16* outb = outp + (long)b * outBatchStride;

  __shared__ float tile[64][66];
  const int t = threadIdx.x;
#pragma unroll
  for (int i = 0; i < 4; ++i) {
    int g = i*256 + t;
    int r = g >> 4, c4 = g & 15;
    float4 v = load4f(inb + (long)(c0 + r)*HW + n0 + c4*4);
    tile[r][c4*4+0] = v.x; tile[r][c4*4+1] = v.y;
    tile[r][c4*4+2] = v.z; tile[r][c4*4+3] = v.w;
  }
  __syncthreads();
#pragma unroll
  for (int i = 0; i < 8; ++i) {
    int g = i*256 + t;
    int n = g >> 5, cu = g & 31;
    unsigned u = (unsigned)bfbits(tile[cu*2][n]) | ((unsigned)bfbits(tile[cu*2+1][n]) << 16);
    *(unsigned*)(outb + (long)(n0 + n)*DIM + c0 + cu*2) = u;
  }
}

// ---------------------------------------------------------------------------
// MFMA GEMM: C[b][m][n] = sum_k A[m][k] * Bt[b][n][k],  n in [0,HW)
// A bf16 row-major (aStride==0 -> shared across b), Bt bf16 [HW][K] per batch.
// Tile 128x128, BK=64, 4 waves (each 64x64), global_load_lds + XOR swizzle.
template<typename TOut>
__global__ __launch_bounds__(256) void gemm_mfma(
    const bf16* __restrict__ A, long aStride,
    const bf16* __restrict__ Bt, TOut* __restrict__ C, int M, int K)
{
  const int b  = blockIdx.z;
  const int m0 = blockIdx.y * 128;
  const int n0 = blockIdx.x * 128;
  const bf16* Ab  = A  + (long)b * aStride;
  const bf16* Btb = Bt + (long)b * (long)HW * K;
  TOut* Cb = C + (long)b * (long)M * HW;

  __shared__ short As[128*64];
  __shared__ short Bs[128*64];

  const int t = threadIdx.x;
  const int w = t >> 6, lane = t & 63;
  const int quad = lane >> 4, l16 = lane & 15;
  const int wm = (w >> 1) * 64, wn = (w & 1) * 64;

  // staging pointers: chunk f = w*256 + i*64 + lane; r=f>>3, p=f&7, c=p^(r&7)
  const bf16* gA[4]; const bf16* gB[4];
#pragma unroll
  for (int i = 0; i < 4; ++i) {
    int f = w*256 + i*64 + lane;
    int r = f >> 3, p = f & 7;
    int c = p ^ (r & 7);
    gA[i] = Ab  + (long)(m0 + r)*K + c*8;
    gB[i] = Btb + (long)(n0 + r)*K + c*8;
  }

  f32x4 acc[4][4] = {};

  for (int k0 = 0; k0 < K; k0 += 64) {
#pragma unroll
    for (int i = 0; i < 4; ++i) {
      GLD_LDS16(gA[i], As + (w*256 + i*64)*8);
      GLD_LDS16(gB[i], Bs + (w*256 + i*64)*8);
      gA[i] += 64; gB[i] += 64;
    }
    __syncthreads();
#pragma unroll
    for (int kk = 0; kk < 2; ++kk) {
      bf16x8 af[4], bfr[4];
      const int sw = (kk*4 + quad) ^ (l16 & 7);
#pragma unroll
      for (int mt = 0; mt < 4; ++mt) {
        af[mt]  = *(const bf16x8*)(As + (wm + mt*16 + l16)*64 + sw*8);
        bfr[mt] = *(const bf16x8*)(Bs + (wn + mt*16 + l16)*64 + sw*8);
      }
#pragma unroll
      for (int mt = 0; mt < 4; ++mt)
#pragma unroll
        for (int nt = 0; nt < 4; ++nt)
          acc[mt][nt] = __builtin_amdgcn_mfma_f32_16x16x32_bf16(af[mt], bfr[nt], acc[mt][nt], 0, 0, 0);
    }
    __syncthreads();
  }

#pragma unroll
  for (int mt = 0; mt < 4; ++mt)
#pragma unroll
    for (int nt = 0; nt < 4; ++nt)
#pragma unroll
      for (int j = 0; j < 4; ++j) {
        int row = m0 + wm + mt*16 + quad*4 + j;
        int col = n0 + wn + nt*16 + l16;
        st(Cb + (long)row*HW + col, acc[mt][nt][j]);
      }
}

// ---------------------------------------------------------------------------
// Depthwise 3x3 SAME, IN-PLACE, one block per (channel, batch) full 128x128
// plane staged in LDS. Also writes per-(b,ch) sum-of-squares for q/k channels.
__global__ __launch_bounds__(256) void dwconv_inplace(
    bf16* __restrict__ qb, bf16* __restrict__ kvb,
    const float* __restrict__ Wdw, float* __restrict__ ssq)
{
  const int ch = blockIdx.x;   // 0..1151 (q:0..383, k:384..767, v:768..1151)
  const int b  = blockIdx.y;
  bf16* plane = (ch < DIM) ? qb + ((long)b*DIM + ch)*HW
                           : kvb + ((long)b*2*DIM + (ch - DIM))*HW;
  float w9[9];
#pragma unroll
  for (int i = 0; i < 9; ++i) w9[i] = Wdw[ch*9 + i];

  __shared__ bf16 t_[128*140];   // pad to 140 shorts/row (280B, 8B aligned)
  const int t = threadIdx.x;
#pragma unroll
  for (int i = 0; i < 16; ++i) {
    int g = i*256 + t;
    int r = g >> 5, c4 = g & 31;
    *(uint2*)&t_[r*140 + c4*4] = *(const uint2*)(plane + r*128 + c4*4);
  }
  __syncthreads();

  const int r = t >> 1, half = t & 1, cbase = half*64;
  const float mtop = (r > 0)   ? 1.f : 0.f;
  const float mbot = (r < 127) ? 1.f : 0.f;
  const int rt = (r > 0)   ? r-1 : r;
  const int rb = (r < 127) ? r+1 : r;

  float a0,a1,a2,b0,b1,b2,c0,c1,c2;
#define LD3(cc, A, B, Cv) { A = __bfloat162float(t_[rt*140 + (cc)]) * mtop; \
                            B = __bfloat162float(t_[r*140 + (cc)]); \
                            Cv = __bfloat162float(t_[rb*140 + (cc)]) * mbot; }
  if (cbase == 0) { a0=b0=c0=0.f; } else LD3(cbase-1, a0, b0, c0);
  LD3(cbase,   a1, b1, c1);
  LD3(cbase+1, a2, b2, c2);

  float ss = 0.f;
  unsigned outu[32];
#pragma unroll 4
  for (int j = 0; j < 64; ++j) {
    float o = w9[0]*a0 + w9[1]*a1 + w9[2]*a2
            + w9[3]*b0 + w9[4]*b1 + w9[5]*b2
            + w9[6]*c0 + w9[7]*c1 + w9[8]*c2;
    ss += o*o;
    unsigned short ob = bfbits(o);
    if (j & 1) outu[j>>1] |= ((unsigned)ob << 16); else outu[j>>1] = ob;
    a0=a1; a1=a2; b0=b1; b1=b2; c0=c1; c1=c2;
    int nc = cbase + j + 2;
    if (nc <= 127) { LD3(nc, a2, b2, c2) } else { a2=b2=c2=0.f; }
  }
#undef LD3

#pragma unroll
  for (int i = 0; i < 8; ++i)
    *(uint4*)(plane + r*128 + cbase + i*8) = *(uint4*)&outu[i*4];

  if (ch < 2*DIM) {
#pragma unroll
    for (int off = 32; off; off >>= 1) ss += __shfl_down(ss, off);
    __shared__ float wsum[4];
    if ((t & 63) == 0) wsum[t >> 6] = ss;
    __syncthreads();
    if (t == 0) ssq[b*2*DIM + ch] = wsum[0]+wsum[1]+wsum[2]+wsum[3];
  }
}

// ---------------------------------------------------------------------------
// S slabs: Sp[split][b][h][48][48] = sum over this split's n-range of q.k^T
// 512 threads = 8 waves; slice = split*8 + wave; 256 n per slice (8 ksteps).
__global__ __launch_bounds__(512) void s_mfma(
    const bf16* __restrict__ qd, const bf16* __restrict__ kd,
    float* __restrict__ Sp)
{
  const int split = blockIdx.x;  // 0..7
  const int h = blockIdx.y, b = blockIdx.z;
  const int t = threadIdx.x, w = t >> 6, lane = t & 63;
  const int quad = lane >> 4, l16 = lane & 15;
  const bf16* qp = qd + ((long)b*DIM + h*CP)*HW;
  const bf16* kp = kd + ((long)b*DIM + h*CP)*HW;
  const int nbase = (split*8 + w) * 256;

  f32x4 acc[3][3] = {};
  for (int ks = 0; ks < 8; ++ks) {
    const int n = nbase + ks*32 + quad*8;
    bf16x8 aq[3], bk[3];
#pragma unroll
    for (int i = 0; i < 3; ++i) {
      aq[i] = *(const bf16x8*)(qp + (long)(i*16 + l16)*HW + n);
      bk[i] = *(const bf16x8*)(kp + (long)(i*16 + l16)*HW + n);
    }
#pragma unroll
    for (int i = 0; i < 3; ++i)
#pragma unroll
      for (int j = 0; j < 3; ++j)
        acc[i][j] = __builtin_amdgcn_mfma_f32_16x16x32_bf16(aq[i], bk[j], acc[i][j], 0, 0, 0);
  }

  __shared__ float Sred[8][CP*CP];
#pragma unroll
  for (int i = 0; i < 3; ++i)
#pragma unroll
    for (int j = 0; j < 3; ++j)
#pragma unroll
      for (int rr = 0; rr < 4; ++rr)
        Sred[w][(i*16 + quad*4 + rr)*CP + j*16 + l16] = acc[i][j][rr];
  __syncthreads();

  float* out = Sp + (long)split*(NB*HEADS*CP*CP) + ((long)(b*HEADS + h))*CP*CP;
  for (int g = t; g < CP*CP; g += 512) {
    float s = 0.f;
#pragma unroll
    for (int ww = 0; ww < 8; ++ww) s += Sred[ww][g];
    out[g] = s;
  }
}

// ---------------------------------------------------------------------------
// logit = (sum slabs) * rsqrt(ssq_q[c]) * rsqrt(ssq_k[d]) * temp[h]; softmax
// over d; writes into slab 0 (attn).
__global__ __launch_bounds__(64) void softmax_attn(
    float* __restrict__ Sp, const float* __restrict__ ssq,
    const float* __restrict__ temp)
{
  const int bhc = blockIdx.x;
  const int c = bhc % CP;
  const int h = (bhc / CP) % HEADS;
  const int b = bhc / (CP * HEADS);
  const int lane = threadIdx.x;
  const long rowoff = ((long)(b*HEADS + h))*CP*CP + c*CP;
  const float rq = rsqrtf(ssq[b*2*DIM + h*CP + c]);
  const float tmp = temp[h];
  float logit = -1e30f;
  if (lane < CP) {
    float s = 0.f;
#pragma unroll
    for (int sl = 0; sl < 8; ++sl) s += Sp[(long)sl*(NB*HEADS*CP*CP) + rowoff + lane];
    float rk = rsqrtf(ssq[b*2*DIM + DIM + h*CP + lane]);
    logit = s * rq * rk * tmp;
  }
  float m = logit;
#pragma unroll
  for (int off = 32; off; off >>= 1) m = fmaxf(m, __shfl_down(m, off));
  m = __shfl(m, 0);
  float e = (lane < CP) ? __expf(logit - m) : 0.f;
  float s = e;
#pragma unroll
  for (int off = 32; off; off >>= 1) s += __shfl_down(s, off);
  s = __shfl(s, 0);
  if (lane < CP) Sp[rowoff + lane] = e / s;
}

// ---------------------------------------------------------------------------
// W2[b, o, h*48+d] = sum_c Wproj[o, h*48+c] * attn[b,h,c,d]   (bf16 out)
__global__ __launch_bounds__(256) void w2fold(
    const float* __restrict__ attn, const float* __restrict__ Wproj,
    bf16* __restrict__ W2)
{
  const int ot = blockIdx.x;  // o-tile of 128 (3 tiles)
  const int h  = blockIdx.y;
  const int b  = blockIdx.z;
  __shared__ float at[CP][CP];
  __shared__ float wp[128][CP];
  const int t = threadIdx.x;
  const float* Ap = attn + ((long)(b*HEADS + h))*CP*CP;
#pragma unroll
  for (int i = 0; i < 9; ++i) {
    int idx = t + 256*i;
    at[idx / CP][idx % CP] = Ap[idx];
  }
#pragma unroll
  for (int i = 0; i < 24; ++i) {
    int idx = t + 256*i;
    int o = idx / CP, c = idx % CP;
    wp[o][c] = Wproj[(long)(ot*128 + o)*DIM + h*CP + c];
  }
  __syncthreads();
#pragma unroll
  for (int i = 0; i < 24; ++i) {
    int idx = t + 256*i;
    int o = idx / CP, d = idx % CP;
    float a = 0.f;
#pragma unroll
    for (int c = 0; c < CP; ++c) a += wp[o][c] * at[c][d];
    W2[((long)b*DIM + ot*128 + o)*DIM + h*CP + d] = f2bf(a);
  }
}

// ---------------------------------------------------------------------------
extern "C" void kernel_launch(void* const* d_in, const int* in_sizes, int n_in,
                              void* d_out, int out_size, void* d_ws, size_t ws_size,
                              hipStream_t stream) {
  const float* x     = (const float*)d_in[0];
  const float* y     = (const float*)d_in[1];
  const float* Wq    = (const float*)d_in[2];
  const float* Wkv   = (const float*)d_in[3];
  const float* Wdw   = (const float*)d_in[4];
  const float* Wproj = (const float*)d_in[5];
  const float* temp  = (const float*)d_in[6];
  float* out = (float*)d_out;

  char* ws = (char*)d_ws;
  const long SZ_T  = 50331648L;                 // one [HW][384] bf16 tensor per 4 batches
  bf16* xT    = (bf16*)(ws + 0L);               // later: vdT
  bf16* yT    = (bf16*)(ws + SZ_T);
  bf16* q_bf  = (bf16*)(ws + 2*SZ_T);           // dwconv in-place -> qd
  bf16* kv_bf = (bf16*)(ws + 3*SZ_T);           // 100663296; in-place -> kd, vd
  char* tail  = ws + 5*SZ_T;                    // 251658240
  bf16* Wq_bf  = (bf16*)(tail);                 // 294912   (dead before Sp)
  bf16* Wkv_bf = (bf16*)(tail + 294912L);       // 589824   (dead before Sp)
  float* Sp    = (float*)(tail);                // 8 slabs x 294912 = 2359296; slab0 -> attn
  bf16* W2_bf  = (bf16*)(tail + 294912L);       // 1179648  (over dead slabs 1-4)
  float* ssq   = (float*)(tail + 2359296L);     // 12288
  bf16* vdT    = xT;
  bf16* vd     = kv_bf + (long)DIM*HW;          // v slice base (batch stride 2*DIM*HW)

  // 1. weights -> bf16
  convert_w<<<864, 256, 0, stream>>>(Wq, Wkv, Wq_bf, Wkv_bf);
  // 2. x,y -> [hw][c] bf16
  transpose_cast<float><<<dim3(HW/64, DIM/64, 8), 256, 0, stream>>>(
      x, y, xT, yT, (long)DIM*HW, (long)HW*DIM);
  // 3. q = Wq @ x
  gemm_mfma<bf16><<<dim3(HW/128, DIM/128, NB), 256, 0, stream>>>(
      Wq_bf, 0, xT, q_bf, DIM, DIM);
  // 4. kv = Wkv @ y
  gemm_mfma<bf16><<<dim3(HW/128, 2*DIM/128, NB), 256, 0, stream>>>(
      Wkv_bf, 0, yT, kv_bf, 2*DIM, DIM);
  // 5. depthwise 3x3 in-place + ssq
  dwconv_inplace<<<dim3(3*DIM, NB), 256, 0, stream>>>(q_bf, kv_bf, Wdw, ssq);
  // 6. vd -> [hw][c]
  transpose_cast<bf16><<<dim3(HW/64, DIM/64, NB), 256, 0, stream>>>(
      vd, nullptr, vdT, nullptr, (long)2*DIM*HW, (long)HW*DIM);
  // 7. raw scores (8 slabs)
  s_mfma<<<dim3(8, HEADS, NB), 512, 0, stream>>>(q_bf, kv_bf, Sp);
  // 8. softmax with folded l2norm + temperature (into slab 0)
  softmax_attn<<<dim3(NB*HEADS*CP), 64, 0, stream>>>(Sp, ssq, temp);
  // 9. fold Wproj through attn -> bf16
  w2fold<<<dim3(3, HEADS, NB), 256, 0, stream>>>(Sp, Wproj, W2_bf);
  // 10. out = W2 @ vd
  gemm_mfma<float><<<dim3(HW/128, DIM/128, NB), 256, 0, stream>>>(
      W2_bf, (long)DIM*DIM, vdT, out, DIM, DIM);
}